// Round 3
// baseline (477.517 us; speedup 1.0000x reference)
//
#include <hip/hip_runtime.h>
#include <cstdint>
#include <cstddef>

typedef __attribute__((ext_vector_type(8))) short short8;
typedef __attribute__((ext_vector_type(4))) float f32x4;

#define D_FEAT 512
#define D_HID  1024
#define NCOL   2048   // hidden cols = 2*D_HID (U | V)
#define NCHUNK 32     // 2048/64 scale chunks per row

__device__ __forceinline__ unsigned short f2bf(float f) {
    unsigned u = __builtin_bit_cast(unsigned, f);
    u += 0x7FFFu + ((u >> 16) & 1u);   // round-to-nearest-even
    return (unsigned short)(u >> 16);
}

// compiler-fence + raw barrier: no implicit vmcnt drain
#define FENCE() asm volatile("" ::: "memory")
#define BAR()   do { FENCE(); __builtin_amdgcn_s_barrier(); FENCE(); } while (0)

// ---------- kernel 1 (fused): cast x fp32->bf16  +  transpose W1 -> w1t ----------
#define NCAST 12500   // (50000*512/8)/256 blocks for the cast half

__global__ __launch_bounds__(256) void prep_kernel(const float* __restrict__ x,
                                                   unsigned short* __restrict__ xb,
                                                   const float* __restrict__ W1,
                                                   unsigned short* __restrict__ w1t,
                                                   int n) {
    if ((int)blockIdx.x < NCAST) {
        int i = (blockIdx.x * 256 + threadIdx.x) * 8;
        if (i >= n) return;
        const float4* xp = (const float4*)(x + i);
        float4 a = xp[0], b = xp[1];
        short8 o;
        o[0] = (short)f2bf(a.x); o[1] = (short)f2bf(a.y);
        o[2] = (short)f2bf(a.z); o[3] = (short)f2bf(a.w);
        o[4] = (short)f2bf(b.x); o[5] = (short)f2bf(b.y);
        o[6] = (short)f2bf(b.z); o[7] = (short)f2bf(b.w);
        *(short8*)(xb + i) = o;
    } else {
        __shared__ float tile[32][33];
        const int bid2 = blockIdx.x - NCAST;          // 0..1023
        const int half = bid2 >> 9;
        const int kb   = ((bid2 >> 5) & 15) * 32;
        const int nb   = (bid2 & 31) * 32;
        const int tx = threadIdx.x & 31, ty = threadIdx.x >> 5;   // 32x8
        #pragma unroll
        for (int i = 0; i < 32; i += 8)
            tile[ty + i][tx] = W1[(size_t)(half * 512 + kb + ty + i) * 1024 + nb + tx];
        __syncthreads();
        #pragma unroll
        for (int i = 0; i < 32; i += 8)
            w1t[(size_t)(half * 1024 + nb + ty + i) * 512 + kb + tx] = f2bf(tile[tx][ty + i]);
    }
}

// ---------- kernel 2: qUV = quant_u8(xb @ w1t^T + b1) — PERSISTENT 256x256 ----------
// Grid = 256 blocks exactly (1/CU). nb = bid&7 (== XCD round-robin: B panel L2-hot per
// XCD); mb = (bid>>3) + 32*i -> 6-7 tiles/block. Block transition cost (exposed drain +
// cold prologue, ~12us/block at 6.125 blocks/CU before) is removed: the next tile's 8
// staging loads are issued BEFORE the epilogue, whose ~2000cy of absmax/quantize VALU
// hides the HBM latency; boundary wait is counted vmcnt(10) (8 epilogue stores + 2
// in-flight loads remain), never a full drain.
// In-loop stream (all -> c^1): ph0:A12(t+1) ph1:A34(t+1) ph2:B12(t+1) ph3:B34(t+1).
// Waits: vmcnt(2) at ph0-end (certifies B34(t)) and ph3-end (certifies A12/A34/B12(t+1));
// vmcnt(0) only at t=7 ph0-end (outstanding is just B34(7)). Cover: A12 3.75 phases,
// A34 2, B12/B34 >=1 phase (L2). Epilogue scratch lives in A1/B1 regions; boundary
// staging targets A0/B0 — disjoint (verified against every in-loop stage target).
#define BM 256
#define BN 256
#define BK 64
#define NB2 (NCOL / BN)  // 8

__global__ __launch_bounds__(512, 2) void gemm_uv_kernel(
    const unsigned short* __restrict__ xb,
    const unsigned short* __restrict__ w1t,
    const float* __restrict__ b1,
    unsigned char* __restrict__ qUV,      // [M][2048] uint8 (biased +128)
    float* __restrict__ scales,           // [M][32] fp32 (duplicated across 16-row groups)
    int M, int MBT)
{
    __shared__ __align__(16) unsigned short smem[65536];   // 128 KiB
    // shorts: A0 [0,16384) | A1 [16384,32768) | B0 [32768,49152) | B1 [49152,65536)

    const int b  = blockIdx.x;
    const int nb = b & 7;
    const int bq = b >> 3;          // 0..31
    const int n0 = nb * BN;

    const int tid  = threadIdx.x;
    const int wave = tid >> 6;
    const int lane = tid & 63;
    const int q    = lane >> 4;
    const int l15  = lane & 15;
    const int wr   = wave >> 2;          // 0..1  (M half)
    const int wc   = wave & 3;           // 0..3  (N quarter)

    const int ar    = lane >> 3;                 // staging row within slot
    const int swcol = ((lane & 7) ^ ar) * 8;     // pre-swizzled global col-group
    const int swz   = l15 & 7;                   // read-side swizzle key

    const int slotA0 = wr * 16 + wc * 4;
    int bslot[4];
    bslot[0] = wc * 8 + wr * 2;     bslot[1] = bslot[0] + 1;
    bslot[2] = wc * 8 + 4 + wr * 2; bslot[3] = bslot[2] + 1;

    int rowA[4], rowB[4];
    #pragma unroll
    for (int j = 0; j < 4; ++j)
        rowB[j] = n0 + bslot[j] * 8 + ar;

    unsigned short* const sAbuf[2] = { smem,         smem + 16384 };
    unsigned short* const sBbuf[2] = { smem + 32768, smem + 49152 };

    auto stageA2 = [&](int t, int cb, int j0) {
        const int k0 = t * BK;
        #pragma unroll
        for (int j = 0; j < 2; ++j)
            __builtin_amdgcn_global_load_lds(
                (const __attribute__((address_space(1))) void*)(xb + ((size_t)rowA[j0 + j] << 9) + k0 + swcol),
                (__attribute__((address_space(3))) void*)(sAbuf[cb] + (slotA0 + j0 + j) * 512),
                16, 0, 0);
    };
    auto stageB2 = [&](int t, int cb, int j0) {
        const int k0 = t * BK;
        #pragma unroll
        for (int j = 0; j < 2; ++j)
            __builtin_amdgcn_global_load_lds(
                (const __attribute__((address_space(1))) void*)(w1t + ((size_t)rowB[j0 + j] << 9) + k0 + swcol),
                (__attribute__((address_space(3))) void*)(sBbuf[cb] + bslot[j0 + j] * 512),
                16, 0, 0);
    };
    auto readA = [&](int cb, int mt, int ks) -> short8 {
        int row = wr * 128 + mt * 16 + l15;
        return *(const short8*)(sAbuf[cb] + row * 64 + (((q | (ks << 2)) ^ swz) * 8));
    };
    auto readB = [&](int cb, int nt, int ks) -> short8 {
        int row = wc * 64 + nt * 16 + l15;
        return *(const short8*)(sBbuf[cb] + row * 64 + (((q | (ks << 2)) ^ swz) * 8));
    };

    // bias pre-load (nb fixed per block -> once)
    float b1v[4];
    #pragma unroll
    for (int nt = 0; nt < 4; ++nt) {
        int n = n0 + wc * 64 + nt * 16 + l15;
        b1v[nt] = (n < D_HID) ? b1[n] : 0.f;
    }
    f32x4 acc[8][4];
    #pragma unroll
    for (int i = 0; i < 8; ++i)
        #pragma unroll
        for (int j = 0; j < 4; ++j)
            acc[i][j] = (f32x4){b1v[j], b1v[j], b1v[j], b1v[j]};

    const float MAGIC = 12583040.0f;   // 1.5*2^23 + 128: low byte = rint(x)+128
    unsigned char* ep8 = (unsigned char*)smem +
        ((wave < 4) ? (32768 + wave * 8192) : (98304 + (wave - 4) * 8192));  // A1|B1 scratch
    const int chunk = (n0 + wc * 64) >> 6;

    // ---- first-tile prologue ----
    int mb = bq;
    #pragma unroll
    for (int j = 0; j < 4; ++j) {
        int m = mb * BM + (slotA0 + j) * 8 + ar;
        rowA[j] = (m < M) ? m : (M - 1);
    }
    stageA2(0, 0, 0); stageA2(0, 0, 2); stageB2(0, 0, 0); stageB2(0, 0, 2);
    asm volatile("s_waitcnt vmcnt(2)" ::: "memory");   // A12,A34,B12(0) ready; B34 in flight
    BAR();

    for (; mb < MBT; mb += 32) {
        const int m0 = mb * BM;

        short8 aR[4][2], bA[2][2], bB[2][2];
        #pragma unroll
        for (int t = 0; t < 8; ++t) {
            const int c = t & 1;

            // ---- phase 0: Q00; stage A12(t+1)->c^1 ----
            #pragma unroll
            for (int mt = 0; mt < 4; ++mt)
                #pragma unroll
                for (int ks = 0; ks < 2; ++ks)
                    aR[mt][ks] = readA(c, mt, ks);
            #pragma unroll
            for (int nt = 0; nt < 2; ++nt)
                #pragma unroll
                for (int ks = 0; ks < 2; ++ks)
                    bA[nt][ks] = readB(c, nt, ks);
            if (t < 7) stageA2(t + 1, c ^ 1, 0);
            BAR();
            __builtin_amdgcn_s_setprio(1);
            #pragma unroll
            for (int ks = 0; ks < 2; ++ks)
                #pragma unroll
                for (int mt = 0; mt < 4; ++mt)
                    #pragma unroll
                    for (int nt = 0; nt < 2; ++nt)
                        acc[mt][nt] = __builtin_amdgcn_mfma_f32_16x16x32_bf16(aR[mt][ks], bA[nt][ks], acc[mt][nt], 0, 0, 0);
            __builtin_amdgcn_s_setprio(0);
            if (t < 7) { asm volatile("s_waitcnt vmcnt(2)" ::: "memory"); }  // B34(t) ready
            else       { asm volatile("s_waitcnt vmcnt(0)" ::: "memory"); }  // B34(7) only
            BAR();

            // ---- phase 1: Q01; stage A34(t+1)->c^1 ----
            #pragma unroll
            for (int nt = 0; nt < 2; ++nt)
                #pragma unroll
                for (int ks = 0; ks < 2; ++ks)
                    bB[nt][ks] = readB(c, 2 + nt, ks);
            if (t < 7) stageA2(t + 1, c ^ 1, 2);
            BAR();
            __builtin_amdgcn_s_setprio(1);
            #pragma unroll
            for (int ks = 0; ks < 2; ++ks)
                #pragma unroll
                for (int mt = 0; mt < 4; ++mt)
                    #pragma unroll
                    for (int nt = 0; nt < 2; ++nt)
                        acc[mt][2 + nt] = __builtin_amdgcn_mfma_f32_16x16x32_bf16(aR[mt][ks], bB[nt][ks], acc[mt][2 + nt], 0, 0, 0);
            __builtin_amdgcn_s_setprio(0);
            BAR();

            // ---- phase 2: Q10; stage B12(t+1)->c^1 ----
            #pragma unroll
            for (int mt = 0; mt < 4; ++mt)
                #pragma unroll
                for (int ks = 0; ks < 2; ++ks)
                    aR[mt][ks] = readA(c, 4 + mt, ks);
            if (t < 7) stageB2(t + 1, c ^ 1, 0);
            BAR();
            __builtin_amdgcn_s_setprio(1);
            #pragma unroll
            for (int ks = 0; ks < 2; ++ks)
                #pragma unroll
                for (int mt = 0; mt < 4; ++mt)
                    #pragma unroll
                    for (int nt = 0; nt < 2; ++nt)
                        acc[4 + mt][nt] = __builtin_amdgcn_mfma_f32_16x16x32_bf16(aR[mt][ks], bA[nt][ks], acc[4 + mt][nt], 0, 0, 0);
            __builtin_amdgcn_s_setprio(0);
            BAR();

            // ---- phase 3: Q11; stage B34(t+1)->c^1 ----
            if (t < 7) stageB2(t + 1, c ^ 1, 2);
            BAR();
            __builtin_amdgcn_s_setprio(1);
            #pragma unroll
            for (int ks = 0; ks < 2; ++ks)
                #pragma unroll
                for (int mt = 0; mt < 4; ++mt)
                    #pragma unroll
                    for (int nt = 0; nt < 2; ++nt)
                        acc[4 + mt][2 + nt] = __builtin_amdgcn_mfma_f32_16x16x32_bf16(aR[mt][ks], bB[nt][ks], acc[4 + mt][2 + nt], 0, 0, 0);
            __builtin_amdgcn_s_setprio(0);
            if (t < 7) { asm volatile("s_waitcnt vmcnt(2)" ::: "memory"); }  // A12,A34,B12(t+1) ready
            BAR();
        }

        // ---- prefetch next tile into buf0 BEFORE epilogue (epilogue VALU hides HBM) ----
        const int mbn = mb + 32;
        const bool hn = (mbn < MBT);
        if (hn) {
            #pragma unroll
            for (int j = 0; j < 4; ++j) {
                int m = mbn * BM + (slotA0 + j) * 8 + ar;
                rowA[j] = (m < M) ? m : (M - 1);
            }
            stageA2(0, 0, 0); stageA2(0, 0, 2); stageB2(0, 0, 0); stageB2(0, 0, 2);
        }

        // ---- epilogue: per-(16-row,64-col) absmax, magic-fmaf uint8 quantize ----
        float msc[8], minv[8];
        #pragma unroll
        for (int mt = 0; mt < 8; ++mt) {
            float m_ = 1e-30f;
            #pragma unroll
            for (int nt = 0; nt < 4; ++nt)
                #pragma unroll
                for (int r = 0; r < 4; ++r)
                    m_ = fmaxf(m_, fabsf(acc[mt][nt][r]));
            #pragma unroll
            for (int off = 1; off < 64; off <<= 1)
                m_ = fmaxf(m_, __shfl_xor(m_, off));
            msc[mt]  = m_ * (1.0f / 127.0f);
            minv[mt] = 127.0f * __builtin_amdgcn_rcpf(m_);
        }
        #pragma unroll
        for (int mt = 0; mt < 8; ++mt)
            #pragma unroll
            for (int nt = 0; nt < 4; ++nt)
                #pragma unroll
                for (int r = 0; r < 4; ++r) {
                    float f = fmaf(acc[mt][nt][r], minv[mt], MAGIC);
                    ep8[(mt * 16 + q * 4 + r) * 64 + ((nt ^ q) * 16) + l15] =
                        (unsigned char)__builtin_bit_cast(unsigned, f);
                }
        #pragma unroll
        for (int h = 0; h < 2; ++h) {
            int srow = m0 + wr * 128 + h * 64 + q * 16 + l15;
            if (srow < M) scales[(size_t)srow * NCHUNK + chunk] = msc[h * 4 + q];
        }
        // same-wave LDS write->read: wave-private region, no barrier needed
        #pragma unroll
        for (int it = 0; it < 8; ++it) {
            int flat = it * 64 + lane;          // 0..511
            int r   = flat >> 2;                // row 0..127
            int cI  = flat & 3;                 // 16B col group
            int m   = m0 + wr * 128 + r;
            if (m < M) {
                int4 v = *(const int4*)(ep8 + r * 64 + ((cI ^ ((r >> 2) & 3)) * 16));
                *(int4*)(qUV + (size_t)m * NCOL + n0 + wc * 64 + cI * 16) = v;
            }
        }

        if (hn) {
            // counted boundary wait: leaves 8 epilogue stores + B34(0) in flight,
            // certifies A12,A34,B12(0) of the prefetched tile
            asm volatile("s_waitcnt vmcnt(10)" ::: "memory");
        }
        BAR();   // scratch reads done block-wide; staged buf0 visible

        if (hn) {
            #pragma unroll
            for (int i = 0; i < 8; ++i)
                #pragma unroll
                for (int j = 0; j < 4; ++j)
                    acc[i][j] = (f32x4){b1v[j], b1v[j], b1v[j], b1v[j]};
        }
    }
}

// ---------- kernel 3: per-edge score = relu(sU*(qU-128) + sV*(qV-128)) . W2 + b2 ----------
__global__ __launch_bounds__(256) void edge_score_kernel(
    const unsigned char* __restrict__ qUV,
    const float* __restrict__ scales,
    const int* __restrict__ src, const int* __restrict__ dst,
    const float* __restrict__ W2, const float* __restrict__ b2,
    float* __restrict__ out, int E)
{
    const int wave = threadIdx.x >> 6;
    const int lane = threadIdx.x & 63;
    const int gw = blockIdx.x * 4 + wave;
    const int e0 = gw * 2;
    const int e1 = e0 + 1;
    if (e0 >= E) return;
    const bool has1 = (e1 < E);

    const int s0 = src[e0];
    const int d0 = dst[e0];
    const int s1 = has1 ? src[e1] : s0;
    const int d1 = has1 ? dst[e1] : d0;

    uint4 qu0 = *(const uint4*)(qUV + (size_t)s0 * NCOL + lane * 16);
    uint4 qv0 = *(const uint4*)(qUV + (size_t)d0 * NCOL + D_HID + lane * 16);
    uint4 qu1 = *(const uint4*)(qUV + (size_t)s1 * NCOL + lane * 16);
    uint4 qv1 = *(const uint4*)(qUV + (size_t)d1 * NCOL + D_HID + lane * 16);
    const int ch = lane >> 2;
    float su0 = scales[(size_t)s0 * NCHUNK + ch];
    float sv0 = scales[(size_t)d0 * NCHUNK + 16 + ch];
    float su1 = scales[(size_t)s1 * NCHUNK + ch];
    float sv1 = scales[(size_t)d1 * NCHUNK + 16 + ch];
    // h = su*(ub-128) + sv*(vb-128) = fmaf(ub,su, fmaf(vb,sv, cc)), cc = -128*(su+sv)
    float cc0 = -128.0f * (su0 + sv0);
    float cc1 = -128.0f * (su1 + sv1);

    const float4* wp = (const float4*)(W2 + lane * 16);
    float4 wa = wp[0], wb = wp[1], wc = wp[2], wd = wp[3];
    float w[16] = {wa.x, wa.y, wa.z, wa.w, wb.x, wb.y, wb.z, wb.w,
                   wc.x, wc.y, wc.z, wc.w, wd.x, wd.y, wd.z, wd.w};
    const float bias = b2[0];

    const unsigned* u0w = (const unsigned*)&qu0; const unsigned* v0w = (const unsigned*)&qv0;
    const unsigned* u1w = (const unsigned*)&qu1; const unsigned* v1w = (const unsigned*)&qv1;

    float acc0 = 0.f, acc1 = 0.f;
    #pragma unroll
    for (int dw = 0; dw < 4; ++dw) {
        #pragma unroll
        for (int b = 0; b < 4; ++b) {
            int k = dw * 4 + b;
            float ub0 = (float)((u0w[dw] >> (8 * b)) & 0xFFu);
            float vb0 = (float)((v0w[dw] >> (8 * b)) & 0xFFu);
            float h0 = fmaf(ub0, su0, fmaf(vb0, sv0, cc0));
            acc0 = fmaf(fmaxf(h0, 0.f), w[k], acc0);
            float ub1 = (float)((u1w[dw] >> (8 * b)) & 0xFFu);
            float vb1 = (float)((v1w[dw] >> (8 * b)) & 0xFFu);
            float h1 = fmaf(ub1, su1, fmaf(vb1, sv1, cc1));
            acc1 = fmaf(fmaxf(h1, 0.f), w[k], acc1);
        }
    }
    #pragma unroll
    for (int off = 1; off < 64; off <<= 1) {
        acc0 += __shfl_xor(acc0, off);
        acc1 += __shfl_xor(acc1, off);
    }
    if (lane == 0) out[e0] = acc0 + bias;
    if (lane == 1 && has1) out[e1] = acc1 + bias;
}

extern "C" void kernel_launch(void* const* d_in, const int* in_sizes, int n_in,
                              void* d_out, int out_size, void* d_ws, size_t ws_size,
                              hipStream_t stream) {
    const float* x   = (const float*)d_in[0];
    const int*   src = (const int*)d_in[1];
    const int*   dst = (const int*)d_in[2];
    const float* W1  = (const float*)d_in[3];
    const float* b1  = (const float*)d_in[4];
    const float* W2  = (const float*)d_in[5];
    const float* b2  = (const float*)d_in[6];
    float* out = (float*)d_out;

    const int M = in_sizes[0] / D_FEAT;   // 50000 nodes
    const int E = in_sizes[1];            // 200000 edges

    // workspace: qUV u8 [M][2048] | scales f32 [M][32] | xb bf16 [M][512] | w1t bf16 [2048][512]
    char* ws = (char*)d_ws;
    unsigned char*  qUV    = (unsigned char*)ws;
    float*          scales = (float*)(ws + (size_t)M * NCOL);
    unsigned short* xb     = (unsigned short*)(ws + (size_t)M * NCOL + (size_t)M * NCHUNK * 4);
    unsigned short* w1t    = (unsigned short*)(ws + (size_t)M * NCOL + (size_t)M * NCHUNK * 4
                                                  + (size_t)M * D_FEAT * 2);

    const int nx = M * D_FEAT;
    prep_kernel<<<NCAST + 1024, 256, 0, stream>>>(x, xb, W1, w1t, nx);
    const int MBT = (M + BM - 1) / BM;
    gemm_uv_kernel<<<256, 512, 0, stream>>>(xb, w1t, b1, qUV, scales, M, MBT);
    edge_score_kernel<<<(E + 7) / 8, 256, 0, stream>>>(qUV, scales, src, dst, W2, b2, out, E);
}

// Round 4
// 332.370 us; speedup vs baseline: 1.4367x; 1.4367x over previous
//
#include <hip/hip_runtime.h>
#include <cstdint>
#include <cstddef>

typedef __attribute__((ext_vector_type(8))) short short8;
typedef __attribute__((ext_vector_type(4))) float f32x4;

#define D_FEAT 512
#define D_HID  1024
#define NCOL   2048   // hidden cols = 2*D_HID (U | V)
#define NCHUNK 32     // 2048/64 scale chunks per row

__device__ __forceinline__ unsigned short f2bf(float f) {
    unsigned u = __builtin_bit_cast(unsigned, f);
    u += 0x7FFFu + ((u >> 16) & 1u);   // round-to-nearest-even
    return (unsigned short)(u >> 16);
}

// ---------- kernel 1 (fused): cast x fp32->bf16  +  transpose W1 -> w1t ----------
#define NCAST 12500   // (50000*512/8)/256 blocks for the cast half

__global__ __launch_bounds__(256) void prep_kernel(const float* __restrict__ x,
                                                   unsigned short* __restrict__ xb,
                                                   const float* __restrict__ W1,
                                                   unsigned short* __restrict__ w1t,
                                                   int n) {
    if ((int)blockIdx.x < NCAST) {
        int i = (blockIdx.x * 256 + threadIdx.x) * 8;
        if (i >= n) return;
        const float4* xp = (const float4*)(x + i);
        float4 a = xp[0], b = xp[1];
        short8 o;
        o[0] = (short)f2bf(a.x); o[1] = (short)f2bf(a.y);
        o[2] = (short)f2bf(a.z); o[3] = (short)f2bf(a.w);
        o[4] = (short)f2bf(b.x); o[5] = (short)f2bf(b.y);
        o[6] = (short)f2bf(b.z); o[7] = (short)f2bf(b.w);
        *(short8*)(xb + i) = o;
    } else {
        __shared__ float tile[32][33];
        const int bid2 = blockIdx.x - NCAST;          // 0..1023
        const int half = bid2 >> 9;
        const int kb   = ((bid2 >> 5) & 15) * 32;
        const int nb   = (bid2 & 31) * 32;
        const int tx = threadIdx.x & 31, ty = threadIdx.x >> 5;   // 32x8
        #pragma unroll
        for (int i = 0; i < 32; i += 8)
            tile[ty + i][tx] = W1[(size_t)(half * 512 + kb + ty + i) * 1024 + nb + tx];
        __syncthreads();
        #pragma unroll
        for (int i = 0; i < 32; i += 8)
            w1t[(size_t)(half * 1024 + nb + ty + i) * 512 + kb + tx] = f2bf(tile[tx][ty + i]);
    }
}

// ---------- kernel 2: qUV = quant_u8(xb @ w1t^T + b1)  with per-(16row,64col) scales ----------
// REVERTED to the proven 128x128 / 4-wave / supergroup structure (119us, MfmaUtil 38.5%).
// Lessons from rounds 1-3: all 256x256 deep-pipeline variants (145/141/266us) lost to this
// structure at K=512; the persistent nb=bid&7 layout put A-sharing blocks on 8 different
// XCDs (FETCH 78->420MB). Supergroup GM=32 keeps A-sharing blocks 32 bids apart = same XCD.
#define BM 128
#define BN 128
#define BK 64
#define GM 32   // m-blocks per supergroup; GM*NB = 512 blocks ~ one residency window

__global__ __launch_bounds__(256, 2) void gemm_uv_kernel(
    const unsigned short* __restrict__ xb,
    const unsigned short* __restrict__ w1t,
    const float* __restrict__ b1,
    unsigned char* __restrict__ qUV,      // [M][2048] uint8 (biased +128)
    float* __restrict__ scales,           // [M][32] fp32 (duplicated across 16-row groups)
    int M, int MB)
{
    __shared__ __align__(16) unsigned short smem[16384];   // 32 KB
    unsigned short* sA = smem;
    unsigned short* sB = smem + 8192;

    const int NB = NCOL / BN;   // 16
    int bid = blockIdx.x;
    int g    = bid / (GM * NB);
    int rem  = bid - g * (GM * NB);
    int base = g * GM;
    int gm   = MB - base; if (gm > GM) gm = GM;
    int mb   = base + rem % gm;
    int nb   = rem / gm;
    const int m0 = mb * BM;
    const int n0 = nb * BN;

    const int tid  = threadIdx.x;
    const int wave = tid >> 6;
    const int lane = tid & 63;
    const int q    = lane >> 4;
    const int l15  = lane & 15;
    const int wm   = (wave >> 1) * 64;
    const int wn   = (wave & 1) * 64;

    const int ar = lane >> 3;
    const int ac = ((lane & 7) ^ ar) * 8;       // swizzled staging col-group

    const int swz = l15 & 7;
    const int c0 = (q ^ swz) * 8;               // ks = 0
    const int c1 = ((q ^ swz) ^ 4) * 8;         // ks = 32

    // bias pre-load: acc is seeded with b1 so the epilogue never adds it
    float b1v[4];
    #pragma unroll
    for (int nt = 0; nt < 4; ++nt) {
        int n = n0 + wn + nt * 16 + l15;
        b1v[nt] = (n < D_HID) ? b1[n] : 0.f;
    }

    f32x4 acc[4][4];
    #pragma unroll
    for (int i = 0; i < 4; ++i)
        #pragma unroll
        for (int j = 0; j < 4; ++j)
            acc[i][j] = (f32x4){b1v[j], b1v[j], b1v[j], b1v[j]};

    #pragma unroll 1
    for (int kt = 0; kt < 8; ++kt) {
        const int k0 = kt * BK;
        __syncthreads();
        #pragma unroll
        for (int i = 0; i < 4; ++i) {
            int slot = wave * 4 + i;
            int row  = slot * 8 + ar;
            int m    = m0 + row; if (m >= M) m = M - 1;
            __builtin_amdgcn_global_load_lds(
                (const __attribute__((address_space(1))) void*)(xb + (size_t)m * D_FEAT + k0 + ac),
                (__attribute__((address_space(3))) void*)(sA + slot * 512),
                16, 0, 0);
        }
        #pragma unroll
        for (int i = 0; i < 4; ++i) {
            int slot = wave * 4 + i;
            int row  = slot * 8 + ar;
            __builtin_amdgcn_global_load_lds(
                (const __attribute__((address_space(1))) void*)(w1t + (size_t)(n0 + row) * D_FEAT + k0 + ac),
                (__attribute__((address_space(3))) void*)(sB + slot * 512),
                16, 0, 0);
        }
        __syncthreads();
        {
            short8 a[4], b[4];
            #pragma unroll
            for (int mt = 0; mt < 4; ++mt)
                a[mt] = *(const short8*)(sA + (wm + mt * 16 + l15) * 64 + c0);
            #pragma unroll
            for (int nt = 0; nt < 4; ++nt)
                b[nt] = *(const short8*)(sB + (wn + nt * 16 + l15) * 64 + c0);
            #pragma unroll
            for (int mt = 0; mt < 4; ++mt)
                #pragma unroll
                for (int nt = 0; nt < 4; ++nt)
                    acc[mt][nt] = __builtin_amdgcn_mfma_f32_16x16x32_bf16(a[mt], b[nt], acc[mt][nt], 0, 0, 0);
            #pragma unroll
            for (int mt = 0; mt < 4; ++mt)
                a[mt] = *(const short8*)(sA + (wm + mt * 16 + l15) * 64 + c1);
            #pragma unroll
            for (int nt = 0; nt < 4; ++nt)
                b[nt] = *(const short8*)(sB + (wn + nt * 16 + l15) * 64 + c1);
            #pragma unroll
            for (int mt = 0; mt < 4; ++mt)
                #pragma unroll
                for (int nt = 0; nt < 4; ++nt)
                    acc[mt][nt] = __builtin_amdgcn_mfma_f32_16x16x32_bf16(a[mt], b[nt], acc[mt][nt], 0, 0, 0);
        }
    }

    // ---- epilogue: per-(16-row,64-col) absmax, magic-fmaf uint8 quantize ----
    float msc[4], minv[4];
    #pragma unroll
    for (int mt = 0; mt < 4; ++mt) {
        float m_ = 1e-30f;
        #pragma unroll
        for (int nt = 0; nt < 4; ++nt)
            #pragma unroll
            for (int r = 0; r < 4; ++r)
                m_ = fmaxf(m_, fabsf(acc[mt][nt][r]));
        #pragma unroll
        for (int off = 1; off < 64; off <<= 1)
            m_ = fmaxf(m_, __shfl_xor(m_, off));
        msc[mt]  = m_ * (1.0f / 127.0f);
        minv[mt] = 127.0f * __builtin_amdgcn_rcpf(m_);
    }

    __syncthreads();   // all waves done reading sA/sB
    unsigned char* ep8 = (unsigned char*)smem + wave * 4096;   // wave-private [64][64] u8
    const float MAGIC = 12583040.0f;   // 1.5*2^23 + 128: low byte = rint(x)+128
    #pragma unroll
    for (int mt = 0; mt < 4; ++mt)
        #pragma unroll
        for (int nt = 0; nt < 4; ++nt)
            #pragma unroll
            for (int r = 0; r < 4; ++r) {
                float f = fmaf(acc[mt][nt][r], minv[mt], MAGIC);
                ep8[(mt * 16 + q * 4 + r) * 64 + nt * 16 + l15] =
                    (unsigned char)__builtin_bit_cast(unsigned, f);
            }
    // branch-free scale store: lane (q,l15) covers row group q, row offset l15
    const int chunk = (n0 + wn) >> 6;
    {
        int srow = m0 + wm + q * 16 + l15;
        if (srow < M) scales[(size_t)srow * NCHUNK + chunk] = msc[q];
    }
    // same-wave LDS write->read: wave-private region, no barrier needed
    #pragma unroll
    for (int i = 0; i < 4; ++i) {
        int flat = i * 64 + lane;          // 0..255
        int r   = flat >> 2;               // row 0..63
        int c16 = (flat & 3) * 16;
        int m   = m0 + wm + r;
        if (m < M) {
            int4 v = *(const int4*)(ep8 + r * 64 + c16);
            *(int4*)(qUV + (size_t)m * NCOL + n0 + wn + c16) = v;
        }
    }
}

// ---------- kernel 3: per-edge score = relu(sU*(qU-128) + sV*(qV-128)) . W2 + b2 ----------
// v2: 4 edges per wave (2 pairs, unrolled). W2 (4KB/wave) + bias hoisted out of the pair
// loop: halves the 400MB of redundant W2 load traffic / issue slots and halves wave count.
// Unrolled pairs give 8 independent 16B row-loads in flight per wave.
__global__ __launch_bounds__(256) void edge_score_kernel(
    const unsigned char* __restrict__ qUV,
    const float* __restrict__ scales,
    const int* __restrict__ src, const int* __restrict__ dst,
    const float* __restrict__ W2, const float* __restrict__ b2,
    float* __restrict__ out, int E)
{
    const int wave = threadIdx.x >> 6;
    const int lane = threadIdx.x & 63;
    const int gw = blockIdx.x * 4 + wave;
    const int ebase = gw * 4;
    if (ebase >= E) return;

    const float4* wp = (const float4*)(W2 + lane * 16);
    float4 wa = wp[0], wb = wp[1], wcv = wp[2], wd = wp[3];
    float w[16] = {wa.x, wa.y, wa.z, wa.w, wb.x, wb.y, wb.z, wb.w,
                   wcv.x, wcv.y, wcv.z, wcv.w, wd.x, wd.y, wd.z, wd.w};
    const float bias = b2[0];
    const int ch = lane >> 2;

    #pragma unroll
    for (int p = 0; p < 2; ++p) {
        const int e0 = ebase + p * 2;
        if (e0 < E) {
            const int e1 = e0 + 1;
            const bool has1 = (e1 < E);

            const int s0 = src[e0];
            const int d0 = dst[e0];
            const int s1 = has1 ? src[e1] : s0;
            const int d1 = has1 ? dst[e1] : d0;

            uint4 qu0 = *(const uint4*)(qUV + (size_t)s0 * NCOL + lane * 16);
            uint4 qv0 = *(const uint4*)(qUV + (size_t)d0 * NCOL + D_HID + lane * 16);
            uint4 qu1 = *(const uint4*)(qUV + (size_t)s1 * NCOL + lane * 16);
            uint4 qv1 = *(const uint4*)(qUV + (size_t)d1 * NCOL + D_HID + lane * 16);
            float su0 = scales[(size_t)s0 * NCHUNK + ch];
            float sv0 = scales[(size_t)d0 * NCHUNK + 16 + ch];
            float su1 = scales[(size_t)s1 * NCHUNK + ch];
            float sv1 = scales[(size_t)d1 * NCHUNK + 16 + ch];
            // h = su*(ub-128) + sv*(vb-128) = fmaf(ub,su, fmaf(vb,sv, cc)), cc = -128*(su+sv)
            float cc0 = -128.0f * (su0 + sv0);
            float cc1 = -128.0f * (su1 + sv1);

            const unsigned* u0w = (const unsigned*)&qu0; const unsigned* v0w = (const unsigned*)&qv0;
            const unsigned* u1w = (const unsigned*)&qu1; const unsigned* v1w = (const unsigned*)&qv1;

            float acc0 = 0.f, acc1 = 0.f;
            #pragma unroll
            for (int dw = 0; dw < 4; ++dw) {
                #pragma unroll
                for (int b = 0; b < 4; ++b) {
                    int k = dw * 4 + b;
                    // (float)((w>>8b)&0xFF) -> v_cvt_f32_ubyte[b]
                    float ub0 = (float)((u0w[dw] >> (8 * b)) & 0xFFu);
                    float vb0 = (float)((v0w[dw] >> (8 * b)) & 0xFFu);
                    float h0 = fmaf(ub0, su0, fmaf(vb0, sv0, cc0));
                    acc0 = fmaf(fmaxf(h0, 0.f), w[k], acc0);
                    float ub1 = (float)((u1w[dw] >> (8 * b)) & 0xFFu);
                    float vb1 = (float)((v1w[dw] >> (8 * b)) & 0xFFu);
                    float h1 = fmaf(ub1, su1, fmaf(vb1, sv1, cc1));
                    acc1 = fmaf(fmaxf(h1, 0.f), w[k], acc1);
                }
            }
            #pragma unroll
            for (int off = 1; off < 64; off <<= 1) {
                acc0 += __shfl_xor(acc0, off);
                acc1 += __shfl_xor(acc1, off);
            }
            if (lane == 0) out[e0] = acc0 + bias;
            if (lane == 1 && has1) out[e1] = acc1 + bias;
        }
    }
}

extern "C" void kernel_launch(void* const* d_in, const int* in_sizes, int n_in,
                              void* d_out, int out_size, void* d_ws, size_t ws_size,
                              hipStream_t stream) {
    const float* x   = (const float*)d_in[0];
    const int*   src = (const int*)d_in[1];
    const int*   dst = (const int*)d_in[2];
    const float* W1  = (const float*)d_in[3];
    const float* b1  = (const float*)d_in[4];
    const float* W2  = (const float*)d_in[5];
    const float* b2  = (const float*)d_in[6];
    float* out = (float*)d_out;

    const int M = in_sizes[0] / D_FEAT;   // 50000 nodes
    const int E = in_sizes[1];            // 200000 edges

    // workspace: qUV u8 [M][2048] | scales f32 [M][32] | xb bf16 [M][512] | w1t bf16 [2048][512]
    char* ws = (char*)d_ws;
    unsigned char*  qUV    = (unsigned char*)ws;
    float*          scales = (float*)(ws + (size_t)M * NCOL);
    unsigned short* xb     = (unsigned short*)(ws + (size_t)M * NCOL + (size_t)M * NCHUNK * 4);
    unsigned short* w1t    = (unsigned short*)(ws + (size_t)M * NCOL + (size_t)M * NCHUNK * 4
                                                  + (size_t)M * D_FEAT * 2);

    const int nx = M * D_FEAT;
    prep_kernel<<<NCAST + 1024, 256, 0, stream>>>(x, xb, W1, w1t, nx);
    const int MB = (M + BM - 1) / BM;
    gemm_uv_kernel<<<MB * (NCOL / BN), 256, 0, stream>>>(xb, w1t, b1, qUV, scales, M, MB);
    edge_score_kernel<<<(E + 15) / 16, 256, 0, stream>>>(qUV, scales, src, dst, W2, b2, out, E);
}